// Round 9
// baseline (753.490 us; speedup 1.0000x reference)
//
#include <hip/hip_runtime.h>
#include <hip/hip_bf16.h>
#include <cstdint>
#include <cstddef>

// ---------------------------------------------------------------------------
// LSTM cell: ht = sigmoid(o) * tanh(sigmoid(f)*c + sigmoid(i)*sigmoid(c~))
// gates = [prev_state, x] @ W'^T with W' row-interleaved: W'[4h+g] = W_g[h].
// Cell update fused into GEMM epilogue (gates never touch HBM).
// GEMM core: 256x256, BK=64, FOUR regions per 2 K-tiles (one barrier each):
//   [reads(12); stage(2 halves); vmcnt(8); 32 MFMA; lgkmcnt(0); BAR]
// RAW: vmcnt(8) certifies the gap-3 stage pair, published by the BAR.
// WAR: trailing lgkmcnt(0) drains this region's reads before the next
// region's stage can overwrite them (gap-1 restage discipline).
// ---------------------------------------------------------------------------

typedef __bf16 nbf16;
typedef nbf16 bf16x8 __attribute__((ext_vector_type(8)));
typedef float f32x4 __attribute__((ext_vector_type(4)));

static constexpr int MDIM = 4096;
static constexpr int NDIM = 8192;
static constexpr int KDIM = 4096;
static constexpr int HDIM = 2048;
static constexpr int KB   = KDIM * 2;     // K row stride in bytes

#define VMW8  asm volatile("s_waitcnt vmcnt(8)" ::: "memory")
#define VMW0  asm volatile("s_waitcnt vmcnt(0)" ::: "memory")
#define LGKM0 asm volatile("s_waitcnt lgkmcnt(0)" ::: "memory")
#define BAR   __builtin_amdgcn_s_barrier()
#define SB0   __builtin_amdgcn_sched_barrier(0)
#define PRIO1 __builtin_amdgcn_s_setprio(1)
#define PRIO0 __builtin_amdgcn_s_setprio(0)

__device__ __forceinline__ void async16(void* lds, const void* g) {
    __builtin_amdgcn_global_load_lds(
        (const __attribute__((address_space(1))) void*)g,
        (__attribute__((address_space(3))) void*)lds,
        16, 0, 0);
}

__device__ __forceinline__ float fsig(float x) {
    return __builtin_amdgcn_rcpf(1.0f + __expf(-x));
}
__device__ __forceinline__ float ftanh(float x) {
    return 2.0f * __builtin_amdgcn_rcpf(1.0f + __expf(-2.0f * x)) - 1.0f;
}

// LDS half = 128 rows x 64 k bf16 = 16 KB; stored chunk = logical ^ (row&7),
// realized as linear LDS dest + inverse-permuted global source (rule 21).
__device__ __forceinline__ void stage_A(const char* Ab, int X, int t, char* slot,
                                        int wave, int r0, int cb) {
    const char* s = Ab + (size_t)(X * 64 + r0) * KB + t * 128 + cb;
    async16(slot + wave * 1024, s);
    async16(slot + (wave + 8) * 1024, s + (size_t)128 * KB);
}
__device__ __forceinline__ void stage_B(const char* Wb, int Y, int t, char* slot,
                                        int wave, int rB0, int cb) {
    const char* s = Wb + (size_t)(rB0 + Y * 32) * KB + t * 128 + cb;
    async16(slot + wave * 1024, s);
    async16(slot + (wave + 8) * 1024, s + (size_t)128 * KB);
}

__device__ __forceinline__ void read_A(bf16x8 (&d)[4][2], const char* hb,
                                       int ar, int kc0, int kc1) {
#pragma unroll
    for (int m = 0; m < 4; ++m) {
        d[m][0] = *(const bf16x8*)(hb + ar + m * 2048 + kc0);
        d[m][1] = *(const bf16x8*)(hb + ar + m * 2048 + kc1);
    }
}
__device__ __forceinline__ void read_B(bf16x8 (&d)[2][2], const char* hb,
                                       int br, int kc0, int kc1) {
#pragma unroll
    for (int j = 0; j < 2; ++j) {
        d[j][0] = *(const bf16x8*)(hb + br + j * 2048 + kc0);
        d[j][1] = *(const bf16x8*)(hb + br + j * 2048 + kc1);
    }
}
__device__ __forceinline__ void mfma16(f32x4 (&acc)[8][4], int mh, int Y,
                                       const bf16x8 (&a)[4][2],
                                       const bf16x8 (&b)[2][2]) {
#pragma unroll
    for (int m = 0; m < 4; ++m)
#pragma unroll
        for (int j = 0; j < 2; ++j) {
            acc[mh * 4 + m][Y * 2 + j] = __builtin_amdgcn_mfma_f32_16x16x32_bf16(
                a[m][0], b[j][0], acc[mh * 4 + m][Y * 2 + j], 0, 0, 0);
            acc[mh * 4 + m][Y * 2 + j] = __builtin_amdgcn_mfma_f32_16x16x32_bf16(
                a[m][1], b[j][1], acc[mh * 4 + m][Y * 2 + j], 0, 0, 0);
        }
}

// ---- concat(prev_state, x) -> bf16 A [MDIM][KDIM] -------------------------
__global__ __launch_bounds__(256) void k_concat_cast(
        const float* __restrict__ prev, const float* __restrict__ x,
        __hip_bfloat16* __restrict__ A) {
    const size_t total8 = (size_t)MDIM * KDIM / 8;
    const size_t stride = (size_t)gridDim.x * blockDim.x;
    for (size_t i = (size_t)blockIdx.x * blockDim.x + threadIdx.x; i < total8;
         i += stride) {
        size_t e = i * 8;
        size_t b = e >> 12;
        int k = (int)(e & (KDIM - 1));
        const float* src = (k < HDIM) ? (prev + b * HDIM + k)
                                      : (x + b * HDIM + (k - HDIM));
        float4 v0 = *(const float4*)src;
        float4 v1 = *(const float4*)(src + 4);
        union { __hip_bfloat16 h[8]; int4 q; } u;
        u.h[0] = __float2bfloat16(v0.x); u.h[1] = __float2bfloat16(v0.y);
        u.h[2] = __float2bfloat16(v0.z); u.h[3] = __float2bfloat16(v0.w);
        u.h[4] = __float2bfloat16(v1.x); u.h[5] = __float2bfloat16(v1.y);
        u.h[6] = __float2bfloat16(v1.z); u.h[7] = __float2bfloat16(v1.w);
        *(int4*)(A + e) = u.q;
    }
}

// ---- gate-interleaved W': row n = W_{n&3}[n>>2], bf16 [NDIM][KDIM] ---------
__global__ __launch_bounds__(256) void k_cast_w(
        const float* __restrict__ w0, const float* __restrict__ w1,
        const float* __restrict__ w2, const float* __restrict__ w3,
        __hip_bfloat16* __restrict__ W) {
    const size_t total8 = (size_t)NDIM * KDIM / 8;
    const size_t stride = (size_t)gridDim.x * blockDim.x;
    for (size_t i = (size_t)blockIdx.x * blockDim.x + threadIdx.x; i < total8;
         i += stride) {
        size_t e = i * 8;
        int n = (int)(e >> 12);
        int k = (int)(e & (KDIM - 1));
        int g = n & 3;
        size_t h = (size_t)(n >> 2);
        const float* src = (g == 0 ? w0 : g == 1 ? w1 : g == 2 ? w2 : w3)
                           + h * KDIM + k;
        float4 v0 = *(const float4*)src;
        float4 v1 = *(const float4*)(src + 4);
        union { __hip_bfloat16 h[8]; int4 q; } u;
        u.h[0] = __float2bfloat16(v0.x); u.h[1] = __float2bfloat16(v0.y);
        u.h[2] = __float2bfloat16(v0.z); u.h[3] = __float2bfloat16(v0.w);
        u.h[4] = __float2bfloat16(v1.x); u.h[5] = __float2bfloat16(v1.y);
        u.h[6] = __float2bfloat16(v1.z); u.h[7] = __float2bfloat16(v1.w);
        *(int4*)(W + e) = u.q;
    }
}

// ---- GEMM + fused LSTM cell epilogue ---------------------------------------
__global__ __launch_bounds__(512, 2) void k_gemm(
        const __hip_bfloat16* __restrict__ A, const __hip_bfloat16* __restrict__ W,
        const float* __restrict__ c, float* __restrict__ out) {
    __shared__ __align__(16) char lds[131072];

    // 2-D XCD swizzle: XCD (bid&7) owns an 8(mt) x 8(nt) sub-grid (bijective)
    const int bid = blockIdx.x;
    const int xcd = bid & 7, j = bid >> 3;
    const int mt = (xcd >> 2) * 8 + (j >> 3);
    const int nt = (xcd & 3) * 8 + (j & 7);
    const int brow = mt * 256, bcol = nt * 256;

    const int tid = threadIdx.x;
    const int wave = tid >> 6, lane = tid & 63;
    const int wr = wave >> 2, wc = wave & 3;

    const char* Ab = (const char*)A + (size_t)brow * KB;
    const char* Wb = (const char*)W + (size_t)bcol * KB;

    char* const Ah00 = lds;
    char* const Ah01 = lds + 16384;
    char* const Ah10 = lds + 32768;
    char* const Ah11 = lds + 49152;
    char* const Bh00 = lds + 65536;
    char* const Bh01 = lds + 81920;
    char* const Bh10 = lds + 98304;
    char* const Bh11 = lds + 114688;

    const int r0  = wave * 8 + (lane >> 3);
    const int rB0 = ((r0 >> 5) << 6) + (r0 & 31);
    const int cb  = (((lane & 7) ^ (lane >> 3)) << 4);
    const int kg  = lane >> 4;
    const int ar  = (wr * 64 + (lane & 15)) * 128;
    const int br  = (wc * 32 + (lane & 15)) * 128;
    const int kc0 = ((kg ^ (lane & 7)) << 4);
    const int kc1 = (((4 + kg) ^ (lane & 7)) << 4);

    f32x4 acc[8][4] = {};
    bf16x8 A0[4][2], B0[2][2];       // A-lo / B-lo of current even tile

    // ---- prologue: stage tiles 0 (s0) and 1 (s1) ----
    stage_B(Wb, 0, 0, Bh00, wave, rB0, cb);
    stage_A(Ab, 0, 0, Ah00, wave, r0, cb);
    stage_A(Ab, 1, 0, Ah01, wave, r0, cb);
    stage_B(Wb, 1, 0, Bh01, wave, rB0, cb);
    stage_B(Wb, 0, 1, Bh10, wave, rB0, cb);
    stage_A(Ab, 0, 1, Ah10, wave, r0, cb);
    stage_A(Ab, 1, 1, Ah11, wave, r0, cb);
    stage_B(Wb, 1, 1, Bh11, wave, rB0, cb);
    VMW8;                     // certify Bh00, Ah00, Ah01, Bh01 (first 8 gll)
    SB0; BAR;
    read_A(A0, Ah00, ar, kc0, kc1);
    read_B(B0, Bh00, br, kc0, kc1);
    LGKM0;                    // drain pre-loop reads before R1 restages Bh00
    SB0; BAR;

    // ---- main loop: 32 iterations x 2 K-tiles, 4 regions, 1 barrier each ----
    for (int i = 0; i < 32; ++i) {
        const int t2 = (2 * i + 2) & 63;
        const int t3 = (2 * i + 3) & 63;
        bf16x8 aH[4][2], bH[2][2], A1[4][2], B1[2][2];

        // R1: tau0 clusters (mh0,Y0)[A0,B0] + (mh1,Y0)[aH,B0]
        read_A(aH, Ah01, ar, kc0, kc1);      // used this region (cluster 2)
        read_B(bH, Bh01, br, kc0, kc1);      // used R2
        stage_B(Wb, 0, t2, Bh00, wave, rB0, cb);
        stage_A(Ab, 0, t2, Ah00, wave, r0, cb);
        VMW8; SB0;
        PRIO1;
        mfma16(acc, 0, 0, A0, B0);
        mfma16(acc, 1, 0, aH, B0);
        PRIO0;
        LGKM0; SB0; BAR;

        // R2: tau0 clusters (mh1,Y1)[aH,bH] + (mh0,Y1)[A0,bH]
        read_B(B1, Bh10, br, kc0, kc1);      // tau1 B-lo, used R3
        read_A(A1, Ah10, ar, kc0, kc1);      // tau1 A-lo, used R3
        stage_A(Ab, 1, t2, Ah01, wave, r0, cb);
        stage_B(Wb, 1, t2, Bh01, wave, rB0, cb);
        VMW8; SB0;
        PRIO1;
        mfma16(acc, 1, 1, aH, bH);
        mfma16(acc, 0, 1, A0, bH);
        PRIO0;
        LGKM0; SB0; BAR;

        // R3: tau1 clusters (mh0,Y0)[A1,B1] + (mh1,Y0)[aH,B1]
        read_A(aH, Ah11, ar, kc0, kc1);      // used this region (cluster 2)
        read_B(bH, Bh11, br, kc0, kc1);      // used R4
        stage_B(Wb, 0, t3, Bh10, wave, rB0, cb);
        stage_A(Ab, 0, t3, Ah10, wave, r0, cb);
        VMW8; SB0;
        PRIO1;
        mfma16(acc, 0, 0, A1, B1);
        mfma16(acc, 1, 0, aH, B1);
        PRIO0;
        LGKM0; SB0; BAR;

        // R4: tau1 clusters (mh1,Y1)[aH,bH] + (mh0,Y1)[A1,bH]
        read_B(B0, Bh00, br, kc0, kc1);      // next-iter tau0 B-lo
        read_A(A0, Ah00, ar, kc0, kc1);      // next-iter tau0 A-lo
        stage_A(Ab, 1, t3, Ah11, wave, r0, cb);
        stage_B(Wb, 1, t3, Bh11, wave, rB0, cb);
        VMW8; SB0;
        PRIO1;
        mfma16(acc, 1, 1, aH, bH);
        mfma16(acc, 0, 1, A1, bH);
        PRIO0;
        LGKM0; SB0; BAR;
    }

    // ---- fused cell epilogue: two 128-row passes through LDS ----
    VMW0; LGKM0;
    BAR;
    __hip_bfloat16* cl = (__hip_bfloat16*)lds;      // [128][256] bf16 = 64 KB
    const int h0 = bcol >> 2;
    #pragma unroll
    for (int p = 0; p < 2; ++p) {
        if (p) BAR;
        if (wr == p) {
            const int rb = ((lane >> 4) << 2);
            const int cbase = wc * 64 + (lane & 15);
            #pragma unroll
            for (int mi = 0; mi < 8; ++mi)
                #pragma unroll
                for (int ni = 0; ni < 4; ++ni)
                    #pragma unroll
                    for (int q = 0; q < 4; ++q)
                        cl[(rb + mi * 16 + q) * 256 + (cbase + ni * 16)] =
                            __float2bfloat16(acc[mi][ni][q]);
        }
        BAR;
        #pragma unroll
        for (int rnd = 0; rnd < 4; ++rnd) {
            const int row = rnd * 32 + (tid >> 4);
            const int ccol = (tid & 15) * 16;
            union { int4 q[2]; __hip_bfloat16 h[16]; } v;
            v.q[0] = *(const int4*)&cl[row * 256 + ccol];
            v.q[1] = *(const int4*)&cl[row * 256 + ccol + 8];
            const size_t R = (size_t)(brow + p * 128 + row);
            const int hh = h0 + (tid & 15) * 4;
            float4 cc = *(const float4*)(c + R * HDIM + hh);
            float cs[4] = {cc.x, cc.y, cc.z, cc.w};
            float ht[4];
            #pragma unroll
            for (int u = 0; u < 4; ++u) {
                float ft  = fsig(__bfloat162float(v.h[4 * u + 0]));
                float it  = fsig(__bfloat162float(v.h[4 * u + 1]));
                float ctt = fsig(__bfloat162float(v.h[4 * u + 2]));
                float ot  = fsig(__bfloat162float(v.h[4 * u + 3]));
                float ct  = ft * cs[u] + it * ctt;
                ht[u] = ot * ftanh(ct);
            }
            float4 o = {ht[0], ht[1], ht[2], ht[3]};
            *(float4*)(out + R * HDIM + hh) = o;
        }
    }
}

extern "C" void kernel_launch(void* const* d_in, const int* in_sizes, int n_in,
                              void* d_out, int out_size, void* d_ws, size_t ws_size,
                              hipStream_t stream) {
    const float* x    = (const float*)d_in[0];
    const float* prev = (const float*)d_in[1];
    const float* cst  = (const float*)d_in[2];
    const float* wfg  = (const float*)d_in[3];
    const float* wig  = (const float*)d_in[4];
    const float* wog  = (const float*)d_in[5];
    const float* wol  = (const float*)d_in[6];
    float* out = (float*)d_out;

    char* ws = (char*)d_ws;
    __hip_bfloat16* Abf = (__hip_bfloat16*)(ws);                 // 32 MB
    __hip_bfloat16* Wbf = (__hip_bfloat16*)(ws + 33554432);      // 64 MB

    k_concat_cast<<<2048, 256, 0, stream>>>(prev, x, Abf);
    k_cast_w<<<2048, 256, 0, stream>>>(wfg, wig, wog, wol, Wbf);
    k_gemm<<<512, 512, 0, stream>>>(Abf, Wbf, cst, out);
}

// Round 10
// 268.005 us; speedup vs baseline: 2.8115x; 2.8115x over previous
//
#include <hip/hip_runtime.h>
#include <hip/hip_bf16.h>
#include <cstdint>
#include <cstddef>

// ---------------------------------------------------------------------------
// LSTM cell: ht = sigmoid(o) * tanh(sigmoid(f)*c + sigmoid(i)*sigmoid(c~))
// gates = [prev_state, x] @ W'^T with W' row-interleaved: W'[4h+g] = W_g[h].
// Cell update fused into GEMM epilogue (gates never touch HBM).
// GEMM core: 256x256, BK=64, 8 regions per 2 K-tiles (round-8 register
// ping-pong, NO extra buffers), but BARRIER ONLY EVERY 2nd REGION:
//   region r: [reads(r); stage(r); vmcnt(8); MFMA(r); lgkmcnt(0); (BAR if r even)]
// RAW: VMW8@e certifies stage(e-5,e-4); reads(r) need stage(r-6); latest
//      barrier e in {r-1,r-2} covers both parities.
// WAR: drain(LGKM0,end r) < BAR < restage(r+2) for all 8 pairs incl. wrap.
// Registers identical to round 8 (no spill — round 9's 4-region variant
// spilled: WRITE_SIZE 38->727 MB was scratch traffic).
// ---------------------------------------------------------------------------

typedef __bf16 nbf16;
typedef nbf16 bf16x8 __attribute__((ext_vector_type(8)));
typedef float f32x4 __attribute__((ext_vector_type(4)));

static constexpr int MDIM = 4096;
static constexpr int NDIM = 8192;
static constexpr int KDIM = 4096;
static constexpr int HDIM = 2048;
static constexpr int KB   = KDIM * 2;     // K row stride in bytes

#define VMW8  asm volatile("s_waitcnt vmcnt(8)" ::: "memory")
#define VMW0  asm volatile("s_waitcnt vmcnt(0)" ::: "memory")
#define LGKM0 asm volatile("s_waitcnt lgkmcnt(0)" ::: "memory")
#define BAR   __builtin_amdgcn_s_barrier()
#define SB0   __builtin_amdgcn_sched_barrier(0)
#define PRIO1 __builtin_amdgcn_s_setprio(1)
#define PRIO0 __builtin_amdgcn_s_setprio(0)

__device__ __forceinline__ void async16(void* lds, const void* g) {
    __builtin_amdgcn_global_load_lds(
        (const __attribute__((address_space(1))) void*)g,
        (__attribute__((address_space(3))) void*)lds,
        16, 0, 0);
}

__device__ __forceinline__ float fsig(float x) {
    return __builtin_amdgcn_rcpf(1.0f + __expf(-x));
}
__device__ __forceinline__ float ftanh(float x) {
    return 2.0f * __builtin_amdgcn_rcpf(1.0f + __expf(-2.0f * x)) - 1.0f;
}

// LDS half = 128 rows x 64 k bf16 = 16 KB; stored chunk = logical ^ (row&7),
// realized as linear LDS dest + inverse-permuted global source (rule 21).
__device__ __forceinline__ void stage_A(const char* Ab, int X, int t, char* slot,
                                        int wave, int r0, int cb) {
    const char* s = Ab + (size_t)(X * 64 + r0) * KB + t * 128 + cb;
    async16(slot + wave * 1024, s);
    async16(slot + (wave + 8) * 1024, s + (size_t)128 * KB);
}
__device__ __forceinline__ void stage_B(const char* Wb, int Y, int t, char* slot,
                                        int wave, int rB0, int cb) {
    const char* s = Wb + (size_t)(rB0 + Y * 32) * KB + t * 128 + cb;
    async16(slot + wave * 1024, s);
    async16(slot + (wave + 8) * 1024, s + (size_t)128 * KB);
}

__device__ __forceinline__ void read_A(bf16x8 (&d)[4][2], const char* hb,
                                       int ar, int kc0, int kc1) {
#pragma unroll
    for (int m = 0; m < 4; ++m) {
        d[m][0] = *(const bf16x8*)(hb + ar + m * 2048 + kc0);
        d[m][1] = *(const bf16x8*)(hb + ar + m * 2048 + kc1);
    }
}
__device__ __forceinline__ void read_B(bf16x8 (&d)[2][2], const char* hb,
                                       int br, int kc0, int kc1) {
#pragma unroll
    for (int j = 0; j < 2; ++j) {
        d[j][0] = *(const bf16x8*)(hb + br + j * 2048 + kc0);
        d[j][1] = *(const bf16x8*)(hb + br + j * 2048 + kc1);
    }
}
__device__ __forceinline__ void mfma16(f32x4 (&acc)[8][4], int mh, int Y,
                                       const bf16x8 (&a)[4][2],
                                       const bf16x8 (&b)[2][2]) {
#pragma unroll
    for (int m = 0; m < 4; ++m)
#pragma unroll
        for (int j = 0; j < 2; ++j) {
            acc[mh * 4 + m][Y * 2 + j] = __builtin_amdgcn_mfma_f32_16x16x32_bf16(
                a[m][0], b[j][0], acc[mh * 4 + m][Y * 2 + j], 0, 0, 0);
            acc[mh * 4 + m][Y * 2 + j] = __builtin_amdgcn_mfma_f32_16x16x32_bf16(
                a[m][1], b[j][1], acc[mh * 4 + m][Y * 2 + j], 0, 0, 0);
        }
}

// ---- concat(prev_state, x) -> bf16 A [MDIM][KDIM] -------------------------
__global__ __launch_bounds__(256) void k_concat_cast(
        const float* __restrict__ prev, const float* __restrict__ x,
        __hip_bfloat16* __restrict__ A) {
    const size_t total8 = (size_t)MDIM * KDIM / 8;
    const size_t stride = (size_t)gridDim.x * blockDim.x;
    for (size_t i = (size_t)blockIdx.x * blockDim.x + threadIdx.x; i < total8;
         i += stride) {
        size_t e = i * 8;
        size_t b = e >> 12;
        int k = (int)(e & (KDIM - 1));
        const float* src = (k < HDIM) ? (prev + b * HDIM + k)
                                      : (x + b * HDIM + (k - HDIM));
        float4 v0 = *(const float4*)src;
        float4 v1 = *(const float4*)(src + 4);
        union { __hip_bfloat16 h[8]; int4 q; } u;
        u.h[0] = __float2bfloat16(v0.x); u.h[1] = __float2bfloat16(v0.y);
        u.h[2] = __float2bfloat16(v0.z); u.h[3] = __float2bfloat16(v0.w);
        u.h[4] = __float2bfloat16(v1.x); u.h[5] = __float2bfloat16(v1.y);
        u.h[6] = __float2bfloat16(v1.z); u.h[7] = __float2bfloat16(v1.w);
        *(int4*)(A + e) = u.q;
    }
}

// ---- gate-interleaved W': row n = W_{n&3}[n>>2], bf16 [NDIM][KDIM] ---------
__global__ __launch_bounds__(256) void k_cast_w(
        const float* __restrict__ w0, const float* __restrict__ w1,
        const float* __restrict__ w2, const float* __restrict__ w3,
        __hip_bfloat16* __restrict__ W) {
    const size_t total8 = (size_t)NDIM * KDIM / 8;
    const size_t stride = (size_t)gridDim.x * blockDim.x;
    for (size_t i = (size_t)blockIdx.x * blockDim.x + threadIdx.x; i < total8;
         i += stride) {
        size_t e = i * 8;
        int n = (int)(e >> 12);
        int k = (int)(e & (KDIM - 1));
        int g = n & 3;
        size_t h = (size_t)(n >> 2);
        const float* src = (g == 0 ? w0 : g == 1 ? w1 : g == 2 ? w2 : w3)
                           + h * KDIM + k;
        float4 v0 = *(const float4*)src;
        float4 v1 = *(const float4*)(src + 4);
        union { __hip_bfloat16 h[8]; int4 q; } u;
        u.h[0] = __float2bfloat16(v0.x); u.h[1] = __float2bfloat16(v0.y);
        u.h[2] = __float2bfloat16(v0.z); u.h[3] = __float2bfloat16(v0.w);
        u.h[4] = __float2bfloat16(v1.x); u.h[5] = __float2bfloat16(v1.y);
        u.h[6] = __float2bfloat16(v1.z); u.h[7] = __float2bfloat16(v1.w);
        *(int4*)(W + e) = u.q;
    }
}

// ---- GEMM + fused LSTM cell epilogue ---------------------------------------
__global__ __launch_bounds__(512, 2) void k_gemm(
        const __hip_bfloat16* __restrict__ A, const __hip_bfloat16* __restrict__ W,
        const float* __restrict__ c, float* __restrict__ out) {
    __shared__ __align__(16) char lds[131072];

    // 2-D XCD swizzle: XCD (bid&7) owns an 8(mt) x 8(nt) sub-grid (bijective)
    const int bid = blockIdx.x;
    const int xcd = bid & 7, j = bid >> 3;
    const int mt = (xcd >> 2) * 8 + (j >> 3);
    const int nt = (xcd & 3) * 8 + (j & 7);
    const int brow = mt * 256, bcol = nt * 256;

    const int tid = threadIdx.x;
    const int wave = tid >> 6, lane = tid & 63;
    const int wr = wave >> 2, wc = wave & 3;

    const char* Ab = (const char*)A + (size_t)brow * KB;
    const char* Wb = (const char*)W + (size_t)bcol * KB;

    char* const Ah00 = lds;
    char* const Ah01 = lds + 16384;
    char* const Ah10 = lds + 32768;
    char* const Ah11 = lds + 49152;
    char* const Bh00 = lds + 65536;
    char* const Bh01 = lds + 81920;
    char* const Bh10 = lds + 98304;
    char* const Bh11 = lds + 114688;

    const int r0  = wave * 8 + (lane >> 3);
    const int rB0 = ((r0 >> 5) << 6) + (r0 & 31);
    const int cb  = (((lane & 7) ^ (lane >> 3)) << 4);
    const int kg  = lane >> 4;
    const int ar  = (wr * 64 + (lane & 15)) * 128;
    const int br  = (wc * 32 + (lane & 15)) * 128;
    const int kc0 = ((kg ^ (lane & 7)) << 4);
    const int kc1 = (((4 + kg) ^ (lane & 7)) << 4);

    f32x4 acc[8][4] = {};
    bf16x8 a0[4][2], a1[4][2], b0[2][2], b1[2][2];

    // ---- prologue: stage tiles 0 (s0) and 1 (s1) ----
    stage_B(Wb, 0, 0, Bh00, wave, rB0, cb);
    stage_A(Ab, 0, 0, Ah00, wave, r0, cb);
    stage_A(Ab, 1, 0, Ah01, wave, r0, cb);
    stage_B(Wb, 1, 0, Bh01, wave, rB0, cb);
    stage_B(Wb, 0, 1, Bh10, wave, rB0, cb);
    stage_A(Ab, 0, 1, Ah10, wave, r0, cb);
    stage_A(Ab, 1, 1, Ah11, wave, r0, cb);
    stage_B(Wb, 1, 1, Bh11, wave, rB0, cb);
    VMW8;                     // certify Bh00, Ah00, Ah01, Bh01 (first 8 gll)
    SB0; BAR;
    read_A(a0, Ah00, ar, kc0, kc1);
    read_B(b0, Bh00, br, kc0, kc1);
    LGKM0;                    // drain pre-loop reads before r1 restages Bh00
    SB0; BAR;                 // "even" boundary anchoring the loop period

    // ---- main loop: 32 iters x 2 K-tiles; 8 regions, BAR every 2nd region --
    for (int i = 0; i < 32; ++i) {
        const int t2 = (2 * i + 2) & 63;
        const int t3 = (2 * i + 3) & 63;

        // r1 (odd, no BAR): reads A-hi(s0)->a1; stage B-lo(s0,t2); MFMA [a0,b0]
        read_A(a1, Ah01, ar, kc0, kc1);
        stage_B(Wb, 0, t2, Bh00, wave, rB0, cb);
        VMW8; SB0;
        PRIO1; mfma16(acc, 0, 0, a0, b0); PRIO0;
        LGKM0; SB0;
        // r2 (even, BAR): reads B-hi(s0)->b1; stage A-lo(s0,t2); MFMA [a1,b0]
        read_B(b1, Bh01, br, kc0, kc1);
        stage_A(Ab, 0, t2, Ah00, wave, r0, cb);
        VMW8; SB0;
        PRIO1; mfma16(acc, 1, 0, a1, b0); PRIO0;
        LGKM0; SB0; BAR;
        // r3 (odd): reads B-lo(s1)->b0; stage A-hi(s0,t2); MFMA [a1,b1]
        read_B(b0, Bh10, br, kc0, kc1);
        stage_A(Ab, 1, t2, Ah01, wave, r0, cb);
        VMW8; SB0;
        PRIO1; mfma16(acc, 1, 1, a1, b1); PRIO0;
        LGKM0; SB0;
        // r4 (even, BAR): reads A-lo(s1)->a1; stage B-hi(s0,t2); MFMA [a0,b1]
        read_A(a1, Ah10, ar, kc0, kc1);
        stage_B(Wb, 1, t2, Bh01, wave, rB0, cb);
        VMW8; SB0;
        PRIO1; mfma16(acc, 0, 1, a0, b1); PRIO0;
        LGKM0; SB0; BAR;
        // r5 (odd): reads A-hi(s1)->a0; stage B-lo(s1,t3); MFMA [a1,b0]
        read_A(a0, Ah11, ar, kc0, kc1);
        stage_B(Wb, 0, t3, Bh10, wave, rB0, cb);
        VMW8; SB0;
        PRIO1; mfma16(acc, 0, 0, a1, b0); PRIO0;
        LGKM0; SB0;
        // r6 (even, BAR): reads B-hi(s1)->b1; stage A-lo(s1,t3); MFMA [a0,b0]
        read_B(b1, Bh11, br, kc0, kc1);
        stage_A(Ab, 0, t3, Ah10, wave, r0, cb);
        VMW8; SB0;
        PRIO1; mfma16(acc, 1, 0, a0, b0); PRIO0;
        LGKM0; SB0; BAR;
        // r7 (odd): reads B-lo(s0,t2)->b0; stage A-hi(s1,t3); MFMA [a0,b1]
        read_B(b0, Bh00, br, kc0, kc1);
        stage_A(Ab, 1, t3, Ah11, wave, r0, cb);
        VMW8; SB0;
        PRIO1; mfma16(acc, 1, 1, a0, b1); PRIO0;
        LGKM0; SB0;
        // r8 (even, BAR): reads A-lo(s0,t2)->a0; stage B-hi(s1,t3); MFMA [a1,b1]
        read_A(a0, Ah00, ar, kc0, kc1);
        stage_B(Wb, 1, t3, Bh11, wave, rB0, cb);
        VMW8; SB0;
        PRIO1; mfma16(acc, 0, 1, a1, b1); PRIO0;
        LGKM0; SB0; BAR;
    }

    // ---- fused cell epilogue: two 128-row passes through LDS ----
    VMW0; LGKM0;
    BAR;
    __hip_bfloat16* cl = (__hip_bfloat16*)lds;      // [128][256] bf16 = 64 KB
    const int h0 = bcol >> 2;
    #pragma unroll
    for (int p = 0; p < 2; ++p) {
        if (p) BAR;
        if (wr == p) {
            const int rb = ((lane >> 4) << 2);
            const int cbase = wc * 64 + (lane & 15);
            #pragma unroll
            for (int mi = 0; mi < 8; ++mi)
                #pragma unroll
                for (int ni = 0; ni < 4; ++ni)
                    #pragma unroll
                    for (int q = 0; q < 4; ++q)
                        cl[(rb + mi * 16 + q) * 256 + (cbase + ni * 16)] =
                            __float2bfloat16(acc[mi][ni][q]);
        }
        BAR;
        #pragma unroll
        for (int rnd = 0; rnd < 4; ++rnd) {
            const int row = rnd * 32 + (tid >> 4);
            const int ccol = (tid & 15) * 16;
            union { int4 q[2]; __hip_bfloat16 h[16]; } v;
            v.q[0] = *(const int4*)&cl[row * 256 + ccol];
            v.q[1] = *(const int4*)&cl[row * 256 + ccol + 8];
            const size_t R = (size_t)(brow + p * 128 + row);
            const int hh = h0 + (tid & 15) * 4;
            float4 cc = *(const float4*)(c + R * HDIM + hh);
            float cs[4] = {cc.x, cc.y, cc.z, cc.w};
            float ht[4];
            #pragma unroll
            for (int u = 0; u < 4; ++u) {
                float ft  = fsig(__bfloat162float(v.h[4 * u + 0]));
                float it  = fsig(__bfloat162float(v.h[4 * u + 1]));
                float ctt = fsig(__bfloat162float(v.h[4 * u + 2]));
                float ot  = fsig(__bfloat162float(v.h[4 * u + 3]));
                float ct  = ft * cs[u] + it * ctt;
                ht[u] = ot * ftanh(ct);
            }
            float4 o = {ht[0], ht[1], ht[2], ht[3]};
            *(float4*)(out + R * HDIM + hh) = o;
        }
    }
}

extern "C" void kernel_launch(void* const* d_in, const int* in_sizes, int n_in,
                              void* d_out, int out_size, void* d_ws, size_t ws_size,
                              hipStream_t stream) {
    const float* x    = (const float*)d_in[0];
    const float* prev = (const float*)d_in[1];
    const float* cst  = (const float*)d_in[2];
    const float* wfg  = (const float*)d_in[3];
    const float* wig  = (const float*)d_in[4];
    const float* wog  = (const float*)d_in[5];
    const float* wol  = (const float*)d_in[6];
    float* out = (float*)d_out;

    char* ws = (char*)d_ws;
    __hip_bfloat16* Abf = (__hip_bfloat16*)(ws);                 // 32 MB
    __hip_bfloat16* Wbf = (__hip_bfloat16*)(ws + 33554432);      // 64 MB

    k_concat_cast<<<2048, 256, 0, stream>>>(prev, x, Abf);
    k_cast_w<<<2048, 256, 0, stream>>>(wfg, wig, wog, wol, Wbf);
    k_gemm<<<512, 512, 0, stream>>>(Abf, Wbf, cst, out);
}

// Round 11
// 266.510 us; speedup vs baseline: 2.8272x; 1.0056x over previous
//
#include <hip/hip_runtime.h>
#include <hip/hip_bf16.h>
#include <cstdint>
#include <cstddef>

// ---------------------------------------------------------------------------
// LSTM cell: ht = sigmoid(o) * tanh(sigmoid(f)*c + sigmoid(i)*sigmoid(c~))
// gates = [prev_state, x] @ W'^T with W' row-interleaved: W'[4h+g] = W_g[h].
// Cell update fused into GEMM epilogue (gates never touch HBM).
// GEMM core: 256x256, BK=64, 8 regions per 2 K-tiles, BAR every 2nd region.
// THIS ROUND (T4 wait-thinning): stage-certification vmcnt only TWICE per
// iteration — vmcnt(4) at ends of r4 and r8 (before their barriers) —
// replacing the per-region vmcnt(8). Ledger: wait@r4 drains to 4 ->
// certifies stages through r2(cur), covering reads r5..r8; wait@r8 covers
// r1..r4 of the next iter. Prologue wait vmcnt(4) certifies the first 6
// halves (closes the old iteration-0 hole at r3's Bh10 read).
// WAR unchanged: per-region trailing lgkmcnt(0) + barrier precede restage.
// ---------------------------------------------------------------------------

typedef __bf16 nbf16;
typedef nbf16 bf16x8 __attribute__((ext_vector_type(8)));
typedef float f32x4 __attribute__((ext_vector_type(4)));

static constexpr int MDIM = 4096;
static constexpr int NDIM = 8192;
static constexpr int KDIM = 4096;
static constexpr int HDIM = 2048;
static constexpr int KB   = KDIM * 2;     // K row stride in bytes

#define VMW4  asm volatile("s_waitcnt vmcnt(4)" ::: "memory")
#define VMW0  asm volatile("s_waitcnt vmcnt(0)" ::: "memory")
#define LGKM0 asm volatile("s_waitcnt lgkmcnt(0)" ::: "memory")
#define BAR   __builtin_amdgcn_s_barrier()
#define SB0   __builtin_amdgcn_sched_barrier(0)
#define PRIO1 __builtin_amdgcn_s_setprio(1)
#define PRIO0 __builtin_amdgcn_s_setprio(0)

__device__ __forceinline__ void async16(void* lds, const void* g) {
    __builtin_amdgcn_global_load_lds(
        (const __attribute__((address_space(1))) void*)g,
        (__attribute__((address_space(3))) void*)lds,
        16, 0, 0);
}

__device__ __forceinline__ float fsig(float x) {
    return __builtin_amdgcn_rcpf(1.0f + __expf(-x));
}
__device__ __forceinline__ float ftanh(float x) {
    return 2.0f * __builtin_amdgcn_rcpf(1.0f + __expf(-2.0f * x)) - 1.0f;
}

// LDS half = 128 rows x 64 k bf16 = 16 KB; stored chunk = logical ^ (row&7),
// realized as linear LDS dest + inverse-permuted global source (rule 21).
__device__ __forceinline__ void stage_A(const char* Ab, int X, int t, char* slot,
                                        int wave, int r0, int cb) {
    const char* s = Ab + (size_t)(X * 64 + r0) * KB + t * 128 + cb;
    async16(slot + wave * 1024, s);
    async16(slot + (wave + 8) * 1024, s + (size_t)128 * KB);
}
__device__ __forceinline__ void stage_B(const char* Wb, int Y, int t, char* slot,
                                        int wave, int rB0, int cb) {
    const char* s = Wb + (size_t)(rB0 + Y * 32) * KB + t * 128 + cb;
    async16(slot + wave * 1024, s);
    async16(slot + (wave + 8) * 1024, s + (size_t)128 * KB);
}

__device__ __forceinline__ void read_A(bf16x8 (&d)[4][2], const char* hb,
                                       int ar, int kc0, int kc1) {
#pragma unroll
    for (int m = 0; m < 4; ++m) {
        d[m][0] = *(const bf16x8*)(hb + ar + m * 2048 + kc0);
        d[m][1] = *(const bf16x8*)(hb + ar + m * 2048 + kc1);
    }
}
__device__ __forceinline__ void read_B(bf16x8 (&d)[2][2], const char* hb,
                                       int br, int kc0, int kc1) {
#pragma unroll
    for (int j = 0; j < 2; ++j) {
        d[j][0] = *(const bf16x8*)(hb + br + j * 2048 + kc0);
        d[j][1] = *(const bf16x8*)(hb + br + j * 2048 + kc1);
    }
}
__device__ __forceinline__ void mfma16(f32x4 (&acc)[8][4], int mh, int Y,
                                       const bf16x8 (&a)[4][2],
                                       const bf16x8 (&b)[2][2]) {
#pragma unroll
    for (int m = 0; m < 4; ++m)
#pragma unroll
        for (int j = 0; j < 2; ++j) {
            acc[mh * 4 + m][Y * 2 + j] = __builtin_amdgcn_mfma_f32_16x16x32_bf16(
                a[m][0], b[j][0], acc[mh * 4 + m][Y * 2 + j], 0, 0, 0);
            acc[mh * 4 + m][Y * 2 + j] = __builtin_amdgcn_mfma_f32_16x16x32_bf16(
                a[m][1], b[j][1], acc[mh * 4 + m][Y * 2 + j], 0, 0, 0);
        }
}

// ---- concat(prev_state, x) -> bf16 A [MDIM][KDIM] -------------------------
__global__ __launch_bounds__(256) void k_concat_cast(
        const float* __restrict__ prev, const float* __restrict__ x,
        __hip_bfloat16* __restrict__ A) {
    const size_t total8 = (size_t)MDIM * KDIM / 8;
    const size_t stride = (size_t)gridDim.x * blockDim.x;
    for (size_t i = (size_t)blockIdx.x * blockDim.x + threadIdx.x; i < total8;
         i += stride) {
        size_t e = i * 8;
        size_t b = e >> 12;
        int k = (int)(e & (KDIM - 1));
        const float* src = (k < HDIM) ? (prev + b * HDIM + k)
                                      : (x + b * HDIM + (k - HDIM));
        float4 v0 = *(const float4*)src;
        float4 v1 = *(const float4*)(src + 4);
        union { __hip_bfloat16 h[8]; int4 q; } u;
        u.h[0] = __float2bfloat16(v0.x); u.h[1] = __float2bfloat16(v0.y);
        u.h[2] = __float2bfloat16(v0.z); u.h[3] = __float2bfloat16(v0.w);
        u.h[4] = __float2bfloat16(v1.x); u.h[5] = __float2bfloat16(v1.y);
        u.h[6] = __float2bfloat16(v1.z); u.h[7] = __float2bfloat16(v1.w);
        *(int4*)(A + e) = u.q;
    }
}

// ---- gate-interleaved W': row n = W_{n&3}[n>>2], bf16 [NDIM][KDIM] ---------
__global__ __launch_bounds__(256) void k_cast_w(
        const float* __restrict__ w0, const float* __restrict__ w1,
        const float* __restrict__ w2, const float* __restrict__ w3,
        __hip_bfloat16* __restrict__ W) {
    const size_t total8 = (size_t)NDIM * KDIM / 8;
    const size_t stride = (size_t)gridDim.x * blockDim.x;
    for (size_t i = (size_t)blockIdx.x * blockDim.x + threadIdx.x; i < total8;
         i += stride) {
        size_t e = i * 8;
        int n = (int)(e >> 12);
        int k = (int)(e & (KDIM - 1));
        int g = n & 3;
        size_t h = (size_t)(n >> 2);
        const float* src = (g == 0 ? w0 : g == 1 ? w1 : g == 2 ? w2 : w3)
                           + h * KDIM + k;
        float4 v0 = *(const float4*)src;
        float4 v1 = *(const float4*)(src + 4);
        union { __hip_bfloat16 h[8]; int4 q; } u;
        u.h[0] = __float2bfloat16(v0.x); u.h[1] = __float2bfloat16(v0.y);
        u.h[2] = __float2bfloat16(v0.z); u.h[3] = __float2bfloat16(v0.w);
        u.h[4] = __float2bfloat16(v1.x); u.h[5] = __float2bfloat16(v1.y);
        u.h[6] = __float2bfloat16(v1.z); u.h[7] = __float2bfloat16(v1.w);
        *(int4*)(W + e) = u.q;
    }
}

// ---- GEMM + fused LSTM cell epilogue ---------------------------------------
__global__ __launch_bounds__(512, 2) void k_gemm(
        const __hip_bfloat16* __restrict__ A, const __hip_bfloat16* __restrict__ W,
        const float* __restrict__ c, float* __restrict__ out) {
    __shared__ __align__(16) char lds[131072];

    // 2-D XCD swizzle: XCD (bid&7) owns an 8(mt) x 8(nt) sub-grid (bijective)
    const int bid = blockIdx.x;
    const int xcd = bid & 7, j = bid >> 3;
    const int mt = (xcd >> 2) * 8 + (j >> 3);
    const int nt = (xcd & 3) * 8 + (j & 7);
    const int brow = mt * 256, bcol = nt * 256;

    const int tid = threadIdx.x;
    const int wave = tid >> 6, lane = tid & 63;
    const int wr = wave >> 2, wc = wave & 3;

    const char* Ab = (const char*)A + (size_t)brow * KB;
    const char* Wb = (const char*)W + (size_t)bcol * KB;

    char* const Ah00 = lds;
    char* const Ah01 = lds + 16384;
    char* const Ah10 = lds + 32768;
    char* const Ah11 = lds + 49152;
    char* const Bh00 = lds + 65536;
    char* const Bh01 = lds + 81920;
    char* const Bh10 = lds + 98304;
    char* const Bh11 = lds + 114688;

    const int r0  = wave * 8 + (lane >> 3);
    const int rB0 = ((r0 >> 5) << 6) + (r0 & 31);
    const int cb  = (((lane & 7) ^ (lane >> 3)) << 4);
    const int kg  = lane >> 4;
    const int ar  = (wr * 64 + (lane & 15)) * 128;
    const int br  = (wc * 32 + (lane & 15)) * 128;
    const int kc0 = ((kg ^ (lane & 7)) << 4);
    const int kc1 = (((4 + kg) ^ (lane & 7)) << 4);

    f32x4 acc[8][4] = {};
    bf16x8 a0[4][2], a1[4][2], b0[2][2], b1[2][2];

    // ---- prologue: stage tiles 0 (s0) and 1 (s1) ----
    stage_B(Wb, 0, 0, Bh00, wave, rB0, cb);
    stage_A(Ab, 0, 0, Ah00, wave, r0, cb);
    stage_A(Ab, 1, 0, Ah01, wave, r0, cb);
    stage_B(Wb, 1, 0, Bh01, wave, rB0, cb);
    stage_B(Wb, 0, 1, Bh10, wave, rB0, cb);
    stage_A(Ab, 0, 1, Ah10, wave, r0, cb);
    stage_A(Ab, 1, 1, Ah11, wave, r0, cb);
    stage_B(Wb, 1, 1, Bh11, wave, rB0, cb);
    VMW4;                     // certify first 12 gll: Bh00,Ah00,Ah01,Bh01,Bh10,Ah10
    SB0; BAR;
    read_A(a0, Ah00, ar, kc0, kc1);
    read_B(b0, Bh00, br, kc0, kc1);
    LGKM0;                    // drain pre-loop reads before r1 restages Bh00
    SB0; BAR;                 // even boundary anchoring the loop period

    // ---- main loop: 32 iters x 2 K-tiles; 8 regions; BAR every 2nd region;
    //      stage-certify vmcnt(4) only at ends of r4 and r8 ----
    for (int i = 0; i < 32; ++i) {
        const int t2 = (2 * i + 2) & 63;
        const int t3 = (2 * i + 3) & 63;

        // r1 (odd): reads A-hi(s0)->a1; stage B-lo(s0,t2); MFMA [a0,b0]
        read_A(a1, Ah01, ar, kc0, kc1);
        stage_B(Wb, 0, t2, Bh00, wave, rB0, cb);
        SB0;
        PRIO1; mfma16(acc, 0, 0, a0, b0); PRIO0;
        LGKM0; SB0;
        // r2 (even, BAR): reads B-hi(s0)->b1; stage A-lo(s0,t2); MFMA [a1,b0]
        read_B(b1, Bh01, br, kc0, kc1);
        stage_A(Ab, 0, t2, Ah00, wave, r0, cb);
        SB0;
        PRIO1; mfma16(acc, 1, 0, a1, b0); PRIO0;
        LGKM0; SB0; BAR;
        // r3 (odd): reads B-lo(s1)->b0; stage A-hi(s0,t2); MFMA [a1,b1]
        read_B(b0, Bh10, br, kc0, kc1);
        stage_A(Ab, 1, t2, Ah01, wave, r0, cb);
        SB0;
        PRIO1; mfma16(acc, 1, 1, a1, b1); PRIO0;
        LGKM0; SB0;
        // r4 (even, VMW4+BAR): reads A-lo(s1)->a1; stage B-hi(s0,t2); MFMA [a0,b1]
        read_A(a1, Ah10, ar, kc0, kc1);
        stage_B(Wb, 1, t2, Bh01, wave, rB0, cb);
        SB0;
        PRIO1; mfma16(acc, 0, 1, a0, b1); PRIO0;
        LGKM0; VMW4; SB0; BAR;
        // r5 (odd): reads A-hi(s1)->a0; stage B-lo(s1,t3); MFMA [a1,b0]
        read_A(a0, Ah11, ar, kc0, kc1);
        stage_B(Wb, 0, t3, Bh10, wave, rB0, cb);
        SB0;
        PRIO1; mfma16(acc, 0, 0, a1, b0); PRIO0;
        LGKM0; SB0;
        // r6 (even, BAR): reads B-hi(s1)->b1; stage A-lo(s1,t3); MFMA [a0,b0]
        read_B(b1, Bh11, br, kc0, kc1);
        stage_A(Ab, 0, t3, Ah10, wave, r0, cb);
        SB0;
        PRIO1; mfma16(acc, 1, 0, a0, b0); PRIO0;
        LGKM0; SB0; BAR;
        // r7 (odd): reads B-lo(s0,t2)->b0; stage A-hi(s1,t3); MFMA [a0,b1]
        read_B(b0, Bh00, br, kc0, kc1);
        stage_A(Ab, 1, t3, Ah11, wave, r0, cb);
        SB0;
        PRIO1; mfma16(acc, 1, 1, a0, b1); PRIO0;
        LGKM0; SB0;
        // r8 (even, VMW4+BAR): reads A-lo(s0,t2)->a0; stage B-hi(s1,t3); MFMA [a1,b1]
        read_A(a0, Ah00, ar, kc0, kc1);
        stage_B(Wb, 1, t3, Bh11, wave, rB0, cb);
        SB0;
        PRIO1; mfma16(acc, 0, 1, a1, b1); PRIO0;
        LGKM0; VMW4; SB0; BAR;
    }

    // ---- fused cell epilogue: two 128-row passes through LDS ----
    VMW0; LGKM0;
    BAR;
    __hip_bfloat16* cl = (__hip_bfloat16*)lds;      // [128][256] bf16 = 64 KB
    const int h0 = bcol >> 2;
    #pragma unroll
    for (int p = 0; p < 2; ++p) {
        if (p) BAR;
        if (wr == p) {
            const int rb = ((lane >> 4) << 2);
            const int cbase = wc * 64 + (lane & 15);
            #pragma unroll
            for (int mi = 0; mi < 8; ++mi)
                #pragma unroll
                for (int ni = 0; ni < 4; ++ni)
                    #pragma unroll
                    for (int q = 0; q < 4; ++q)
                        cl[(rb + mi * 16 + q) * 256 + (cbase + ni * 16)] =
                            __float2bfloat16(acc[mi][ni][q]);
        }
        BAR;
        #pragma unroll
        for (int rnd = 0; rnd < 4; ++rnd) {
            const int row = rnd * 32 + (tid >> 4);
            const int ccol = (tid & 15) * 16;
            union { int4 q[2]; __hip_bfloat16 h[16]; } v;
            v.q[0] = *(const int4*)&cl[row * 256 + ccol];
            v.q[1] = *(const int4*)&cl[row * 256 + ccol + 8];
            const size_t R = (size_t)(brow + p * 128 + row);
            const int hh = h0 + (tid & 15) * 4;
            float4 cc = *(const float4*)(c + R * HDIM + hh);
            float cs[4] = {cc.x, cc.y, cc.z, cc.w};
            float ht[4];
            #pragma unroll
            for (int u = 0; u < 4; ++u) {
                float ft  = fsig(__bfloat162float(v.h[4 * u + 0]));
                float it  = fsig(__bfloat162float(v.h[4 * u + 1]));
                float ctt = fsig(__bfloat162float(v.h[4 * u + 2]));
                float ot  = fsig(__bfloat162float(v.h[4 * u + 3]));
                float ct  = ft * cs[u] + it * ctt;
                ht[u] = ot * ftanh(ct);
            }
            float4 o = {ht[0], ht[1], ht[2], ht[3]};
            *(float4*)(out + R * HDIM + hh) = o;
        }
    }
}

extern "C" void kernel_launch(void* const* d_in, const int* in_sizes, int n_in,
                              void* d_out, int out_size, void* d_ws, size_t ws_size,
                              hipStream_t stream) {
    const float* x    = (const float*)d_in[0];
    const float* prev = (const float*)d_in[1];
    const float* cst  = (const float*)d_in[2];
    const float* wfg  = (const float*)d_in[3];
    const float* wig  = (const float*)d_in[4];
    const float* wog  = (const float*)d_in[5];
    const float* wol  = (const float*)d_in[6];
    float* out = (float*)d_out;

    char* ws = (char*)d_ws;
    __hip_bfloat16* Abf = (__hip_bfloat16*)(ws);                 // 32 MB
    __hip_bfloat16* Wbf = (__hip_bfloat16*)(ws + 33554432);      // 64 MB

    k_concat_cast<<<2048, 256, 0, stream>>>(prev, x, Abf);
    k_cast_w<<<2048, 256, 0, stream>>>(wfg, wig, wog, wol, Wbf);
    k_gemm<<<512, 512, 0, stream>>>(Abf, Wbf, cst, out);
}